// Round 9
// baseline (260.778 us; speedup 1.0000x reference)
//
#include <hip/hip_runtime.h>
#include <math.h>

#define NC 722
#define NF2 361            // float2 per row; rows 8B-aligned
#define NROWS 65536
#define WAVES_PER_BLOCK 4
#define ROWS_PER_WAVE 16
#define GROUPS 8           // 8 groups x 2 rows, double-buffered
#define KITERS 6           // ceil(361/64)
#define ROWS_PER_BLOCK (WAVES_PER_BLOCK * ROWS_PER_WAVE)   // 64
#define NBLOCKS (NROWS / ROWS_PER_BLOCK)                    // 1024

__global__ __launch_bounds__(256) void ce_gauss_kernel(
        const float* __restrict__ pred,
        const int* __restrict__ target,
        float* __restrict__ partials) {
    const int lane = threadIdx.x & 63;
    const int wave = threadIdx.x >> 6;
    __shared__ float wave_sums[WAVES_PER_BLOCK];

    // Each wave owns 16 contiguous rows; all 1024 blocks co-resident
    // (~80 VGPR -> 6 waves/SIMD > the 16 waves/CU needed) => no block churn,
    // and the double-buffer below keeps loads in flight through all compute.
    const int wrow0 = (blockIdx.x * WAVES_PER_BLOCK + wave) * ROWS_PER_WAVE;

    // float2 index per k (same for every row); clamp only affects k=5,lane>40
    int idxk[KITERS];
    #pragma unroll
    for (int k = 0; k < KITERS; ++k) {
        int idx = lane + (k << 6);
        idxk[k] = (idx > NF2 - 1) ? (NF2 - 1) : idx;
    }

    float2 vbuf[2][2][KITERS];   // [buffer][row-in-group][k]

    // ---- prologue: load group 0 ----
    {
        const float2* __restrict__ pA = (const float2*)(pred + (size_t)(wrow0 + 0) * NC);
        const float2* __restrict__ pB = (const float2*)(pred + (size_t)(wrow0 + 1) * NC);
        #pragma unroll
        for (int k = 0; k < KITERS; ++k) {
            vbuf[0][0][k] = pA[idxk[k]];
            vbuf[0][1][k] = pB[idxk[k]];
        }
    }

    // lane roles for the tap phase (rows 0..1 of each group on lanes 0..15)
    const int  grr = (lane >> 3) & 1;
    const int  gj  = lane & 7;
    const bool lane_live = (lane < 16);
    int ad = gj - 3; ad = (ad < 0) ? -ad : ad;      // |gj-3|
    // Closed-form smoothed label: w(c) = DECAYS[|c-t|], center 1.0 (the
    // reference overwrite-scatter's last writer is always smallest-dist).
    const float w = (ad == 0) ? 1.0f
                  : (ad == 1) ? 0.606530659713f     // exp(-1/2)
                  : (ad == 2) ? 0.367879441171f     // exp(-1)
                  : (ad == 3) ? 0.135335283237f     // exp(-2)
                  : 0.0f;                           // gj==7 slot

    float contrib = 0.f;

    #pragma unroll
    for (int g = 0; g < GROUPS; ++g) {
        const int buf = g & 1;
        // ---- prefetch group g+1 into the other buffer ----
        if (g + 1 < GROUPS) {
            const float2* __restrict__ pA =
                (const float2*)(pred + (size_t)(wrow0 + 2 * (g + 1)) * NC);
            const float2* __restrict__ pB =
                (const float2*)(pred + (size_t)(wrow0 + 2 * (g + 1) + 1) * NC);
            #pragma unroll
            for (int k = 0; k < KITERS; ++k) {
                vbuf[buf ^ 1][0][k] = pA[idxk[k]];
                vbuf[buf ^ 1][1][k] = pB[idxk[k]];
            }
        }

        // ---- compute group g ----
        float seA = 0.f, seB = 0.f;
        #pragma unroll
        for (int k = 0; k < KITERS; ++k) {
            const bool valid = (k < KITERS - 1) || (lane < NF2 - 5 * 64); // lane<41
            const float sA = __expf(vbuf[buf][0][k].x) + __expf(vbuf[buf][0][k].y);
            const float sB = __expf(vbuf[buf][1][k].x) + __expf(vbuf[buf][1][k].y);
            seA += valid ? sA : 0.f;
            seB += valid ? sB : 0.f;
        }
        #pragma unroll
        for (int off = 32; off > 0; off >>= 1) {
            seA += __shfl_xor(seA, off, 64);
            seB += __shfl_xor(seB, off, 64);
        }

        const int tA = target[wrow0 + 2 * g];        // wave-uniform s_loads
        const int tB = target[wrow0 + 2 * g + 1];
        const float se_sel = grr ? seB : seA;
        const int   t_sel  = grr ? tB : tA;
        const int c = t_sel - 3 + gj;
        const bool tap_valid = lane_live & (gj < 7) & (c >= 0) & (c <= NC - 1);
        int cc = c; if (cc < 0) cc = 0; if (cc > NC - 1) cc = NC - 1;
        const float pv = pred[(size_t)(wrow0 + 2 * g + grr) * NC + cc]; // cache-hot
        const float lse = __logf(se_sel);
        contrib += tap_valid ? (w * (lse - pv)) : 0.f;  // deferred reduce
    }

    // ---- one wave butterfly at the end, then block sum ----
    #pragma unroll
    for (int off = 32; off > 0; off >>= 1)
        contrib += __shfl_xor(contrib, off, 64);
    if (lane == 0) wave_sums[wave] = contrib;
    __syncthreads();
    if (threadIdx.x == 0) {
        partials[blockIdx.x] =
            wave_sums[0] + wave_sums[1] + wave_sums[2] + wave_sums[3];
    }
}

__global__ __launch_bounds__(256) void reduce_partials_kernel(
        const float* __restrict__ partials, float* __restrict__ out) {
    const int lane = threadIdx.x & 63;
    const int wave = threadIdx.x >> 6;
    __shared__ float ws[4];

    float s = 0.f;
    #pragma unroll
    for (int k = 0; k < NBLOCKS / 256; ++k)          // 4 coalesced iters
        s += partials[threadIdx.x + (k << 8)];
    #pragma unroll
    for (int off = 32; off > 0; off >>= 1)
        s += __shfl_xor(s, off, 64);
    if (lane == 0) ws[wave] = s;
    __syncthreads();
    if (threadIdx.x == 0)
        out[0] = (ws[0] + ws[1] + ws[2] + ws[3]) * (1.0f / (float)NROWS);
}

extern "C" void kernel_launch(void* const* d_in, const int* in_sizes, int n_in,
                              void* d_out, int out_size, void* d_ws, size_t ws_size,
                              hipStream_t stream) {
    const float* pred = (const float*)d_in[0];
    const int* target = (const int*)d_in[1];
    float* out = (float*)d_out;
    float* partials = (float*)d_ws;   // 1024 floats = 4 KB

    ce_gauss_kernel<<<NBLOCKS, 256, 0, stream>>>(pred, target, partials);
    reduce_partials_kernel<<<1, 256, 0, stream>>>(partials, out);
}